// Round 1
// baseline (222.263 us; speedup 1.0000x reference)
//
#include <hip/hip_runtime.h>

#define T_TOKENS 16384
#define DIM 2048
#define NE 8
#define QOUT 2048
#define LSCALE 2.0f

typedef __attribute__((ext_vector_type(4))) float f32x4;
typedef __attribute__((ext_vector_type(8))) short s16x8;

__device__ __forceinline__ short f2bf(float f) {
  unsigned u = __builtin_bit_cast(unsigned, f);
  u += 0x7fffu + ((u >> 16) & 1u);   // round-to-nearest-even
  return (short)(u >> 16);
}

__device__ __forceinline__ s16x8 pack8(float4 a, float4 b) {
  s16x8 r;
  r[0] = f2bf(a.x); r[1] = f2bf(a.y); r[2] = f2bf(a.z); r[3] = f2bf(a.w);
  r[4] = f2bf(b.x); r[5] = f2bf(b.y); r[6] = f2bf(b.z); r[7] = f2bf(b.w);
  return r;
}

// ---------------------------------------------------------------------------
// Pack LoRA weights (f32) into bf16 MFMA-B-fragment-friendly layout.
// lora_a [E][D][R]  -> P1[d8][col=e*16+r][j]  (d = d8*8+j), col in [0,128)
// lora_b [E][R][QO] -> P2[k8][c][j]           (k = k8*8+j = e*16+r), c in [0,2048)
// Both give a lane's 8 k-contiguous bf16 as one aligned 16B load.
// ---------------------------------------------------------------------------
__global__ __launch_bounds__(256) void k_pack(
    const float* __restrict__ qa, const float* __restrict__ qb,
    const float* __restrict__ va, const float* __restrict__ vb,
    short* __restrict__ Bq1, short* __restrict__ Bv1,
    short* __restrict__ Bq2, short* __restrict__ Bv2) {
  int tid = blockIdx.x * 256 + threadIdx.x;  // 131072 threads
  if (tid < 65536) {
    int mat = tid >> 15;            // 0 = q, 1 = v
    int idx = tid & 32767;          // d8*128 + col
    int d8 = idx >> 7, c = idx & 127;
    int e = c >> 4, r = c & 15;
    const float* src = mat ? va : qa;
    short* dst = mat ? Bv1 : Bq1;
    s16x8 v;
#pragma unroll
    for (int j = 0; j < 8; ++j)
      v[j] = f2bf(src[((size_t)e * DIM + d8 * 8 + j) * 16 + r]);
    *(s16x8*)(dst + (size_t)idx * 8) = v;
  } else {
    int t2 = tid - 65536;
    int mat = t2 >> 15;
    int idx = t2 & 32767;           // k8*2048 + c
    int k8 = idx >> 11, c = idx & 2047;
    const float* src = mat ? vb : qb;
    short* dst = mat ? Bv2 : Bq2;
    s16x8 v;
#pragma unroll
    for (int j = 0; j < 8; ++j)
      v[j] = f2bf(src[(size_t)(k8 * 8 + j) * QOUT + c]);
    *(s16x8*)(dst + (size_t)idx * 8) = v;
  }
}

// ---------------------------------------------------------------------------
// Routing: f32-exact logits, softmax, top-2, normalized scores * SCALE.
// One wave per token. Output: dense w[T][8] (0 for unselected experts).
// ---------------------------------------------------------------------------
__global__ __launch_bounds__(256) void k_route(
    const float* __restrict__ h, const float* __restrict__ rw,
    float* __restrict__ wout) {
  const int lane = threadIdx.x & 63, wv = threadIdx.x >> 6;
  const int t = blockIdx.x * 4 + wv;
  const float* hp = h + (size_t)t * DIM;
  float4 hl[8];
#pragma unroll
  for (int i = 0; i < 8; ++i) hl[i] = *(const float4*)(hp + i * 256 + lane * 4);
  float lg[NE];
#pragma unroll
  for (int e = 0; e < NE; ++e) {
    const float* wp = rw + (size_t)e * DIM;
    float acc = 0.f;
#pragma unroll
    for (int i = 0; i < 8; ++i) {
      float4 w4 = *(const float4*)(wp + i * 256 + lane * 4);
      acc += hl[i].x * w4.x + hl[i].y * w4.y + hl[i].z * w4.z + hl[i].w * w4.w;
    }
#pragma unroll
    for (int s = 32; s; s >>= 1) acc += __shfl_xor(acc, s, 64);
    lg[e] = acc;
  }
  float mx = lg[0];
#pragma unroll
  for (int e = 1; e < NE; ++e) mx = fmaxf(mx, lg[e]);
  float p[NE], sum = 0.f;
#pragma unroll
  for (int e = 0; e < NE; ++e) { p[e] = expf(lg[e] - mx); sum += p[e]; }
  // top-2, ties -> lower index (matches lax.top_k)
  int i1 = 0; float v1 = p[0];
#pragma unroll
  for (int e = 1; e < NE; ++e) if (p[e] > v1) { v1 = p[e]; i1 = e; }
  float v2 = -1.f; int i2 = 0;
#pragma unroll
  for (int e = 0; e < NE; ++e) if (e != i1 && p[e] > v2) { v2 = p[e]; i2 = e; }
  float s1 = v1 / sum, s2 = v2 / sum;
  float dn = s1 + s2 + 1e-20f;
  float w1 = s1 / dn * LSCALE, w2 = s2 / dn * LSCALE;
  if (lane < NE) {
    float wo = (lane == i1) ? w1 : ((lane == i2) ? w2 : 0.f);
    wout[(size_t)t * NE + lane] = wo;
  }
}

// ---------------------------------------------------------------------------
// Stage 1: low = (h @ Acat) * w.  Block = 32 tokens x 256 cols (q:0-127 v:128-255)
// 4 waves split cols (64 each). 16x16x32 bf16 MFMA, K=2048.
// Epilogue scales by w[t][e] (includes top-2 mask + SCALE), stores bf16 [T][128].
// ---------------------------------------------------------------------------
__global__ __launch_bounds__(256) void k_low(
    const float* __restrict__ h,
    const short* __restrict__ Bq1, const short* __restrict__ Bv1,
    const float* __restrict__ wdense,
    short* __restrict__ lowq, short* __restrict__ lowv) {
  const int lane = threadIdx.x & 63, wv = threadIdx.x >> 6;
  const int lrow = lane & 15, lk = lane >> 4;
  const int row0 = blockIdx.x * 32;
  const int c0 = wv * 64;
  f32x4 acc[2][4] = {};
  for (int kb = 0; kb < DIM; kb += 32) {
    s16x8 a[2];
#pragma unroll
    for (int rt = 0; rt < 2; ++rt) {
      const float* ap = h + (size_t)(row0 + rt * 16 + lrow) * DIM + kb + lk * 8;
      float4 f0 = *(const float4*)ap;
      float4 f1 = *(const float4*)(ap + 4);
      a[rt] = pack8(f0, f1);
    }
    s16x8 b[4];
#pragma unroll
    for (int ct = 0; ct < 4; ++ct) {
      int c = c0 + ct * 16 + lrow;
      int cc = c & 127;
      const short* bp = (c < 128) ? Bq1 : Bv1;
      int d8 = (kb >> 3) + lk;
      b[ct] = *(const s16x8*)(bp + ((size_t)d8 * 128 + cc) * 8);
    }
#pragma unroll
    for (int rt = 0; rt < 2; ++rt)
#pragma unroll
      for (int ct = 0; ct < 4; ++ct)
        acc[rt][ct] = __builtin_amdgcn_mfma_f32_16x16x32_bf16(a[rt], b[ct], acc[rt][ct], 0, 0, 0);
  }
#pragma unroll
  for (int rt = 0; rt < 2; ++rt)
#pragma unroll
    for (int ct = 0; ct < 4; ++ct) {
      int c = c0 + ct * 16 + lrow;
      int cc = c & 127;
      int e = cc >> 4;
      short* op = (c < 128) ? lowq : lowv;
#pragma unroll
      for (int j = 0; j < 4; ++j) {
        int t = row0 + rt * 16 + lk * 4 + j;
        float wgt = wdense[(size_t)t * NE + e];
        op[(size_t)t * 128 + cc] = f2bf(acc[rt][ct][j] * wgt);
      }
    }
}

// ---------------------------------------------------------------------------
// Stage 2: delta = low[T,128] @ B[128,2048].  Block = 64 tokens x 256 cols.
// grid.y: 16 = {q,v} x 8 col-tiles. f32 stores straight to d_out.
// ---------------------------------------------------------------------------
__global__ __launch_bounds__(256) void k_up(
    const short* __restrict__ lowq, const short* __restrict__ lowv,
    const short* __restrict__ Bq2, const short* __restrict__ Bv2,
    float* __restrict__ out) {
  const int lane = threadIdx.x & 63, wv = threadIdx.x >> 6;
  const int lrow = lane & 15, lk = lane >> 4;
  const int row0 = blockIdx.x * 64;
  const int m = blockIdx.y >> 3;
  const int cb = (blockIdx.y & 7) * 256 + wv * 64;
  const short* low = m ? lowv : lowq;
  const short* B = m ? Bv2 : Bq2;
  float* op = out + (size_t)m * T_TOKENS * QOUT;
  f32x4 acc[4][4] = {};
#pragma unroll
  for (int kb = 0; kb < 128; kb += 32) {
    s16x8 a[4], b[4];
#pragma unroll
    for (int rt = 0; rt < 4; ++rt)
      a[rt] = *(const s16x8*)(low + (size_t)(row0 + rt * 16 + lrow) * 128 + kb + lk * 8);
#pragma unroll
    for (int ct = 0; ct < 4; ++ct) {
      int c = cb + ct * 16 + lrow;
      int k8 = (kb >> 3) + lk;
      b[ct] = *(const s16x8*)(B + ((size_t)k8 * QOUT + c) * 8);
    }
#pragma unroll
    for (int rt = 0; rt < 4; ++rt)
#pragma unroll
      for (int ct = 0; ct < 4; ++ct)
        acc[rt][ct] = __builtin_amdgcn_mfma_f32_16x16x32_bf16(a[rt], b[ct], acc[rt][ct], 0, 0, 0);
  }
#pragma unroll
  for (int rt = 0; rt < 4; ++rt)
#pragma unroll
    for (int ct = 0; ct < 4; ++ct) {
      int c = cb + ct * 16 + lrow;
#pragma unroll
      for (int j = 0; j < 4; ++j) {
        int t = row0 + rt * 16 + lk * 4 + j;
        op[(size_t)t * QOUT + c] = acc[rt][ct][j];
      }
    }
}

extern "C" void kernel_launch(void* const* d_in, const int* in_sizes, int n_in,
                              void* d_out, int out_size, void* d_ws, size_t ws_size,
                              hipStream_t stream) {
  const float* h  = (const float*)d_in[0];
  const float* rw = (const float*)d_in[1];
  const float* qa = (const float*)d_in[2];
  const float* qb = (const float*)d_in[3];
  const float* va = (const float*)d_in[4];
  const float* vb = (const float*)d_in[5];
  float* out = (float*)d_out;
  char* ws = (char*)d_ws;

  float* wdense = (float*)ws;                         // 512 KB  (T*8 f32)
  short* Bq1 = (short*)(ws + (512  << 10));           // 512 KB each
  short* Bv1 = (short*)(ws + (1024 << 10));
  short* Bq2 = (short*)(ws + (1536 << 10));
  short* Bv2 = (short*)(ws + (2048 << 10));
  short* lowq = (short*)(ws + (2560 << 10));          // 4 MB each (T*128 bf16)
  short* lowv = (short*)(ws + (2560 << 10) + (4 << 20));

  k_pack<<<512, 256, 0, stream>>>(qa, qb, va, vb, Bq1, Bv1, Bq2, Bv2);
  k_route<<<T_TOKENS / 4, 256, 0, stream>>>(h, rw, wdense);
  k_low<<<T_TOKENS / 32, 256, 0, stream>>>(h, Bq1, Bv1, wdense, lowq, lowv);
  dim3 g2(T_TOKENS / 64, 16);
  k_up<<<g2, 256, 0, stream>>>(lowq, lowv, Bq2, Bv2, out);
}

// Round 2
// 210.470 us; speedup vs baseline: 1.0560x; 1.0560x over previous
//
#include <hip/hip_runtime.h>

#define T_TOKENS 16384
#define DIM 2048
#define NE 8
#define QOUT 2048
#define LSCALE 2.0f

typedef __attribute__((ext_vector_type(4))) float f32x4;
typedef __attribute__((ext_vector_type(8))) short s16x8;
typedef __attribute__((ext_vector_type(4))) short s16x4;

__device__ __forceinline__ short f2bf(float f) {
  unsigned u = __builtin_bit_cast(unsigned, f);
  u += 0x7fffu + ((u >> 16) & 1u);   // round-to-nearest-even
  return (short)(u >> 16);
}

__device__ __forceinline__ s16x8 pack8(float4 a, float4 b) {
  s16x8 r;
  r[0] = f2bf(a.x); r[1] = f2bf(a.y); r[2] = f2bf(a.z); r[3] = f2bf(a.w);
  r[4] = f2bf(b.x); r[5] = f2bf(b.y); r[6] = f2bf(b.z); r[7] = f2bf(b.w);
  return r;
}

// ---------------------------------------------------------------------------
// Pack LoRA weights (f32) into bf16 MFMA-fragment layout.
// lora_a [E][D][R]  -> P1[d8][col=e*16+r][j]  (d = d8*8+j), col in [0,128)
// lora_b [E][R][QO] -> P2[k8][c][j]           (k = k8*8+j = e*16+r)
// ---------------------------------------------------------------------------
__global__ __launch_bounds__(256) void k_pack(
    const float* __restrict__ qa, const float* __restrict__ qb,
    const float* __restrict__ va, const float* __restrict__ vb,
    short* __restrict__ Bq1, short* __restrict__ Bv1,
    short* __restrict__ Bq2, short* __restrict__ Bv2) {
  int tid = blockIdx.x * 256 + threadIdx.x;  // 131072 threads
  if (tid < 65536) {
    int mat = tid >> 15;
    int idx = tid & 32767;          // d8*128 + col
    int d8 = idx >> 7, c = idx & 127;
    int e = c >> 4, r = c & 15;
    const float* src = mat ? va : qa;
    short* dst = mat ? Bv1 : Bq1;
    s16x8 v;
#pragma unroll
    for (int j = 0; j < 8; ++j)
      v[j] = f2bf(src[((size_t)e * DIM + d8 * 8 + j) * 16 + r]);
    *(s16x8*)(dst + (size_t)idx * 8) = v;
  } else {
    int t2 = tid - 65536;
    int mat = t2 >> 15;
    int idx = t2 & 32767;           // k8*2048 + c
    int k8 = idx >> 11, c = idx & 2047;
    const float* src = mat ? vb : qb;
    short* dst = mat ? Bv2 : Bq2;
    s16x8 v;
#pragma unroll
    for (int j = 0; j < 8; ++j)
      v[j] = f2bf(src[(size_t)(k8 * 8 + j) * QOUT + c]);
    *(s16x8*)(dst + (size_t)idx * 8) = v;
  }
}

// ---------------------------------------------------------------------------
// Prep: f32-exact routing (softmax, top-2, normalized*SCALE) -> dense w[T][8];
// optionally also emits h in bf16 (WB=1) so the GEMM never re-reads f32 h.
// One wave per token.
// ---------------------------------------------------------------------------
template <int WB>
__global__ __launch_bounds__(256) void k_prep(
    const float* __restrict__ h, const float* __restrict__ rw,
    float* __restrict__ wout, short* __restrict__ hb) {
  const int lane = threadIdx.x & 63, wv = threadIdx.x >> 6;
  const int t = blockIdx.x * 4 + wv;
  const float* hp = h + (size_t)t * DIM;
  float4 hl[8];
#pragma unroll
  for (int i = 0; i < 8; ++i) hl[i] = *(const float4*)(hp + i * 256 + lane * 4);
  if (WB) {
#pragma unroll
    for (int i = 0; i < 8; ++i) {
      s16x4 v;
      v[0] = f2bf(hl[i].x); v[1] = f2bf(hl[i].y);
      v[2] = f2bf(hl[i].z); v[3] = f2bf(hl[i].w);
      *(s16x4*)(hb + (size_t)t * DIM + i * 256 + lane * 4) = v;
    }
  }
  float lg[NE];
#pragma unroll
  for (int e = 0; e < NE; ++e) {
    const float* wp = rw + (size_t)e * DIM;
    float acc = 0.f;
#pragma unroll
    for (int i = 0; i < 8; ++i) {
      float4 w4 = *(const float4*)(wp + i * 256 + lane * 4);
      acc += hl[i].x * w4.x + hl[i].y * w4.y + hl[i].z * w4.z + hl[i].w * w4.w;
    }
#pragma unroll
    for (int s = 32; s; s >>= 1) acc += __shfl_xor(acc, s, 64);
    lg[e] = acc;
  }
  float mx = lg[0];
#pragma unroll
  for (int e = 1; e < NE; ++e) mx = fmaxf(mx, lg[e]);
  float p[NE], sum = 0.f;
#pragma unroll
  for (int e = 0; e < NE; ++e) { p[e] = expf(lg[e] - mx); sum += p[e]; }
  int i1 = 0; float v1 = p[0];
#pragma unroll
  for (int e = 1; e < NE; ++e) if (p[e] > v1) { v1 = p[e]; i1 = e; }
  float v2 = -1.f; int i2 = 0;
#pragma unroll
  for (int e = 0; e < NE; ++e) if (e != i1 && p[e] > v2) { v2 = p[e]; i2 = e; }
  float s1 = v1 / sum, s2 = v2 / sum;
  float dn = s1 + s2 + 1e-20f;
  float w1 = s1 / dn * LSCALE, w2 = s2 / dn * LSCALE;
  if (lane < NE) {
    float wo = (lane == i1) ? w1 : ((lane == i2) ? w2 : 0.f);
    wout[(size_t)t * NE + lane] = wo;
  }
}

// ---------------------------------------------------------------------------
// Stage 1: low = (h @ Acat) * w.  Block = 32 tokens x 256 cols, 4 waves.
// Operand-swapped MFMA: C reg axis runs along LoRA cols -> short4 stores and
// a single wdense load per fragment.  B16=1: read bf16 h; else convert f32.
// ---------------------------------------------------------------------------
template <int B16>
__global__ __launch_bounds__(256) void k_low(
    const float* __restrict__ hf, const short* __restrict__ hb,
    const short* __restrict__ Bq1, const short* __restrict__ Bv1,
    const float* __restrict__ wdense,
    short* __restrict__ lowq, short* __restrict__ lowv) {
  const int lane = threadIdx.x & 63, wv = threadIdx.x >> 6;
  const int lrow = lane & 15, lk = lane >> 4;
  const int row0 = blockIdx.x * 32;
  const int c0 = wv * 64;
  f32x4 acc[2][4] = {};
  for (int kb = 0; kb < DIM; kb += 32) {
    s16x8 a[2];
#pragma unroll
    for (int rt = 0; rt < 2; ++rt) {
      if (B16) {
        a[rt] = *(const s16x8*)(hb + (size_t)(row0 + rt * 16 + lrow) * DIM + kb + lk * 8);
      } else {
        const float* ap = hf + (size_t)(row0 + rt * 16 + lrow) * DIM + kb + lk * 8;
        a[rt] = pack8(*(const float4*)ap, *(const float4*)(ap + 4));
      }
    }
    s16x8 b[4];
#pragma unroll
    for (int ct = 0; ct < 4; ++ct) {
      int c = c0 + ct * 16 + lrow;
      int cc = c & 127;
      const short* bp = (c < 128) ? Bq1 : Bv1;
      int d8 = (kb >> 3) + lk;
      b[ct] = *(const s16x8*)(bp + ((size_t)d8 * 128 + cc) * 8);
    }
#pragma unroll
    for (int rt = 0; rt < 2; ++rt)
#pragma unroll
      for (int ct = 0; ct < 4; ++ct)
        acc[rt][ct] = __builtin_amdgcn_mfma_f32_16x16x32_bf16(b[ct], a[rt], acc[rt][ct], 0, 0, 0);
  }
#pragma unroll
  for (int rt = 0; rt < 2; ++rt)
#pragma unroll
    for (int ct = 0; ct < 4; ++ct) {
      int t = row0 + rt * 16 + lrow;           // token from C's lane&15 axis
      int col = c0 + ct * 16 + lk * 4;         // 4 consecutive LoRA cols
      int cc = col & 127;
      int e = cc >> 4;
      short* op = (col < 128) ? lowq : lowv;
      float wgt = wdense[(size_t)t * NE + e];
      s16x4 v;
#pragma unroll
      for (int j = 0; j < 4; ++j) v[j] = f2bf(acc[rt][ct][j] * wgt);
      *(s16x4*)(op + (size_t)t * 128 + cc) = v;
    }
}

// ---------------------------------------------------------------------------
// Stage 2: delta = low[T,128] @ B[128,2048].  Block = 64 tokens x 256 cols.
// Operand-swapped MFMA -> float4 stores straight to d_out.
// ---------------------------------------------------------------------------
__global__ __launch_bounds__(256) void k_up(
    const short* __restrict__ lowq, const short* __restrict__ lowv,
    const short* __restrict__ Bq2, const short* __restrict__ Bv2,
    float* __restrict__ out) {
  const int lane = threadIdx.x & 63, wv = threadIdx.x >> 6;
  const int lrow = lane & 15, lk = lane >> 4;
  const int row0 = blockIdx.x * 64;
  const int m = blockIdx.y >> 3;
  const int cb = (blockIdx.y & 7) * 256 + wv * 64;
  const short* low = m ? lowv : lowq;
  const short* B = m ? Bv2 : Bq2;
  float* op = out + (size_t)m * T_TOKENS * QOUT;
  f32x4 acc[4][4] = {};
#pragma unroll
  for (int kb = 0; kb < 128; kb += 32) {
    s16x8 a[4], b[4];
#pragma unroll
    for (int rt = 0; rt < 4; ++rt)
      a[rt] = *(const s16x8*)(low + (size_t)(row0 + rt * 16 + lrow) * 128 + kb + lk * 8);
#pragma unroll
    for (int ct = 0; ct < 4; ++ct) {
      int c = cb + ct * 16 + lrow;
      int k8 = (kb >> 3) + lk;
      b[ct] = *(const s16x8*)(B + ((size_t)k8 * QOUT + c) * 8);
    }
#pragma unroll
    for (int rt = 0; rt < 4; ++rt)
#pragma unroll
      for (int ct = 0; ct < 4; ++ct)
        acc[rt][ct] = __builtin_amdgcn_mfma_f32_16x16x32_bf16(b[ct], a[rt], acc[rt][ct], 0, 0, 0);
  }
#pragma unroll
  for (int rt = 0; rt < 4; ++rt)
#pragma unroll
    for (int ct = 0; ct < 4; ++ct) {
      int t = row0 + rt * 16 + lrow;           // token
      int col = cb + ct * 16 + lk * 4;         // 4 consecutive out cols
      *(f32x4*)(op + (size_t)t * QOUT + col) = acc[rt][ct];
    }
}

extern "C" void kernel_launch(void* const* d_in, const int* in_sizes, int n_in,
                              void* d_out, int out_size, void* d_ws, size_t ws_size,
                              hipStream_t stream) {
  const float* h  = (const float*)d_in[0];
  const float* rw = (const float*)d_in[1];
  const float* qa = (const float*)d_in[2];
  const float* qb = (const float*)d_in[3];
  const float* va = (const float*)d_in[4];
  const float* vb = (const float*)d_in[5];
  float* out = (float*)d_out;
  char* ws = (char*)d_ws;

  float* wdense = (float*)ws;                         // 512 KB
  short* Bq1 = (short*)(ws + (512  << 10));           // 512 KB each
  short* Bv1 = (short*)(ws + (1024 << 10));
  short* Bq2 = (short*)(ws + (1536 << 10));
  short* Bv2 = (short*)(ws + (2048 << 10));
  short* lowq = (short*)(ws + (2560 << 10));          // 4 MB each
  short* lowv = (short*)(ws + (2560 << 10) + (4 << 20));
  short* hb16 = (short*)(ws + (2560 << 10) + (8 << 20));  // 64 MB
  const size_t need = ((size_t)2560 << 10) + ((size_t)8 << 20) + ((size_t)T_TOKENS * DIM * 2);
  const bool fast = ws_size >= need;

  k_pack<<<512, 256, 0, stream>>>(qa, qb, va, vb, Bq1, Bv1, Bq2, Bv2);
  if (fast) {
    k_prep<1><<<T_TOKENS / 4, 256, 0, stream>>>(h, rw, wdense, hb16);
    k_low<1><<<T_TOKENS / 32, 256, 0, stream>>>(h, hb16, Bq1, Bv1, wdense, lowq, lowv);
  } else {
    k_prep<0><<<T_TOKENS / 4, 256, 0, stream>>>(h, rw, wdense, hb16);
    k_low<0><<<T_TOKENS / 32, 256, 0, stream>>>(h, hb16, Bq1, Bv1, wdense, lowq, lowv);
  }
  dim3 g2(T_TOKENS / 64, 16);
  k_up<<<g2, 256, 0, stream>>>(lowq, lowv, Bq2, Bv2, out);
}

// Round 3
// 155.729 us; speedup vs baseline: 1.4272x; 1.3515x over previous
//
#include <hip/hip_runtime.h>

#define T_TOKENS 16384
#define DIM 2048
#define NE 8
#define QOUT 2048
#define LSCALE 2.0f

typedef __attribute__((ext_vector_type(4))) float f32x4;
typedef __attribute__((ext_vector_type(8))) short s16x8;
typedef __attribute__((ext_vector_type(4))) short s16x4;

__device__ __forceinline__ short f2bf(float f) {
  unsigned u = __builtin_bit_cast(unsigned, f);
  u += 0x7fffu + ((u >> 16) & 1u);   // round-to-nearest-even
  return (short)(u >> 16);
}

// ---------------------------------------------------------------------------
// Pack LoRA weights (f32) into bf16 MFMA-fragment layout.
// lora_a [E][D][R]  -> P1[d8][col=e*16+r][j]  (d = d8*8+j), col in [0,128)
// lora_b [E][R][QO] -> P2[k8][c][j]           (k = k8*8+j = e*16+r)
// ---------------------------------------------------------------------------
__global__ __launch_bounds__(256) void k_pack(
    const float* __restrict__ qa, const float* __restrict__ qb,
    const float* __restrict__ va, const float* __restrict__ vb,
    short* __restrict__ Bq1, short* __restrict__ Bv1,
    short* __restrict__ Bq2, short* __restrict__ Bv2) {
  int tid = blockIdx.x * 256 + threadIdx.x;  // 131072 threads
  if (tid < 65536) {
    int mat = tid >> 15;
    int idx = tid & 32767;          // d8*128 + col
    int d8 = idx >> 7, c = idx & 127;
    int e = c >> 4, r = c & 15;
    const float* src = mat ? va : qa;
    short* dst = mat ? Bv1 : Bq1;
    s16x8 v;
#pragma unroll
    for (int j = 0; j < 8; ++j)
      v[j] = f2bf(src[((size_t)e * DIM + d8 * 8 + j) * 16 + r]);
    *(s16x8*)(dst + (size_t)idx * 8) = v;
  } else {
    int t2 = tid - 65536;
    int mat = t2 >> 15;
    int idx = t2 & 32767;           // k8*2048 + c
    int k8 = idx >> 11, c = idx & 2047;
    const float* src = mat ? vb : qb;
    short* dst = mat ? Bv2 : Bq2;
    s16x8 v;
#pragma unroll
    for (int j = 0; j < 8; ++j)
      v[j] = f2bf(src[(size_t)(k8 * 8 + j) * QOUT + c]);
    *(s16x8*)(dst + (size_t)idx * 8) = v;
  }
}

// ---------------------------------------------------------------------------
// Fused stage 1: routing (f32-exact) + low = (h @ Acat) * w.
// Block = 32 tokens x 256 cols, 4 waves (wave wv -> cols wv*64..+63).
// Per K-step(32): each thread loads ONE distinct float4 of the 32x32 f32 h
// tile (row r=tid>>3, k off kq=(tid&7)*4), accumulates router logits in f32
// (rw staged in LDS), converts to bf16 into a double-buffered LDS A-tile;
// waves read MFMA A-frags from LDS.  Epilogue: shfl-reduce logits, softmax,
// top-2, normalized*SCALE -> w in LDS -> scale acc frags -> bf16 low.
// ---------------------------------------------------------------------------
__global__ __launch_bounds__(256) void k_s1(
    const float* __restrict__ h, const float* __restrict__ rw,
    const short* __restrict__ Bq1, const short* __restrict__ Bv1,
    short* __restrict__ lowq, short* __restrict__ lowv) {
  __shared__ float rwl[NE * DIM];       // 64 KB
  __shared__ short At[2][32][40];       // padded: 80B rows, 16B-aligned frags
  __shared__ float wl[32][NE];

  const int tid = threadIdx.x;
  const int lane = tid & 63, wv = tid >> 6;
  const int lrow = lane & 15, lk = lane >> 4;
  const int row0 = blockIdx.x * 32;
  const int c0 = wv * 64;
  const int r = tid >> 3;              // block row 0..31
  const int kq = (tid & 7) * 4;        // k offset 0,4,..,28

  {  // stage router weights (f32, 16384 elems) into LDS
    const float4* src = (const float4*)rw;
    float4* dst = (float4*)rwl;
#pragma unroll
    for (int i = 0; i < 16; ++i) dst[tid + i * 256] = src[tid + i * 256];
  }
  __syncthreads();

  float lg[NE] = {0.f, 0.f, 0.f, 0.f, 0.f, 0.f, 0.f, 0.f};
  f32x4 acc[2][4] = {};
  int cur = 0;
  const float* hrow = h + (size_t)(row0 + r) * DIM + kq;

  for (int kb = 0; kb < DIM; kb += 32) {
    float4 hv = *(const float4*)(hrow + kb);
    // routing partials (f32 VALU, co-issues with MFMA)
#pragma unroll
    for (int e = 0; e < NE; ++e) {
      float4 rv = *(const float4*)&rwl[e * DIM + kb + kq];
      lg[e] += hv.x * rv.x + hv.y * rv.y + hv.z * rv.z + hv.w * rv.w;
    }
    // convert + stage A tile
    s16x4 hb4;
    hb4[0] = f2bf(hv.x); hb4[1] = f2bf(hv.y);
    hb4[2] = f2bf(hv.z); hb4[3] = f2bf(hv.w);
    *(s16x4*)&At[cur][r][kq] = hb4;
    // B fragments (global, L2-resident)
    s16x8 b[4];
#pragma unroll
    for (int ct = 0; ct < 4; ++ct) {
      int c = c0 + ct * 16 + lrow;
      int cc = c & 127;
      const short* bp = (c < 128) ? Bq1 : Bv1;
      b[ct] = *(const s16x8*)(bp + ((size_t)((kb >> 3) + lk) * 128 + cc) * 8);
    }
    __syncthreads();
    s16x8 a[2];
#pragma unroll
    for (int rt = 0; rt < 2; ++rt)
      a[rt] = *(const s16x8*)&At[cur][rt * 16 + lrow][lk * 8];
#pragma unroll
    for (int rt = 0; rt < 2; ++rt)
#pragma unroll
      for (int ct = 0; ct < 4; ++ct)
        acc[rt][ct] = __builtin_amdgcn_mfma_f32_16x16x32_bf16(b[ct], a[rt], acc[rt][ct], 0, 0, 0);
    cur ^= 1;
  }

  // reduce logits across the 8 k-lanes of each row (lanes are consecutive)
#pragma unroll
  for (int e = 0; e < NE; ++e) {
    lg[e] += __shfl_xor(lg[e], 1, 64);
    lg[e] += __shfl_xor(lg[e], 2, 64);
    lg[e] += __shfl_xor(lg[e], 4, 64);
  }
  // softmax + top-2 (redundant across the 8 lanes of a row; deterministic)
  float mx = lg[0];
#pragma unroll
  for (int e = 1; e < NE; ++e) mx = fmaxf(mx, lg[e]);
  float p[NE], sum = 0.f;
#pragma unroll
  for (int e = 0; e < NE; ++e) { p[e] = expf(lg[e] - mx); sum += p[e]; }
  int i1 = 0; float v1 = p[0];
#pragma unroll
  for (int e = 1; e < NE; ++e) if (p[e] > v1) { v1 = p[e]; i1 = e; }
  float v2 = -1.f; int i2 = 0;
#pragma unroll
  for (int e = 0; e < NE; ++e) if (e != i1 && p[e] > v2) { v2 = p[e]; i2 = e; }
  float s1 = v1 / sum, s2 = v2 / sum;
  float dn = s1 + s2 + 1e-20f;
  float w1 = s1 / dn * LSCALE, w2 = s2 / dn * LSCALE;
  int el = tid & 7;
  wl[r][el] = (el == i1) ? w1 : ((el == i2) ? w2 : 0.f);
  __syncthreads();

  // scale + store low (operand-swapped layout: token=lane&15, cols=lk*4+j)
#pragma unroll
  for (int rt = 0; rt < 2; ++rt)
#pragma unroll
    for (int ct = 0; ct < 4; ++ct) {
      int t = row0 + rt * 16 + lrow;
      int col = c0 + ct * 16 + lk * 4;
      int cc = col & 127;
      int e = cc >> 4;
      short* op = (col < 128) ? lowq : lowv;
      float wgt = wl[rt * 16 + lrow][e];
      s16x4 v;
#pragma unroll
      for (int j = 0; j < 4; ++j) v[j] = f2bf(acc[rt][ct][j] * wgt);
      *(s16x4*)(op + (size_t)t * 128 + cc) = v;
    }
}

// ---------------------------------------------------------------------------
// Stage 2: delta = low[T,128] @ B[128,2048].  Block = 64 tokens x 1024 cols.
// A-frags (full K=128) preloaded in registers; 4 serial 256-col subtiles
// (4 waves x 64 cols each) -> low re-read 2x instead of 8x.
// grid = (T/64, 4); y = m*2 + half.
// ---------------------------------------------------------------------------
__global__ __launch_bounds__(256) void k_up(
    const short* __restrict__ lowq, const short* __restrict__ lowv,
    const short* __restrict__ Bq2, const short* __restrict__ Bv2,
    float* __restrict__ out) {
  const int lane = threadIdx.x & 63, wv = threadIdx.x >> 6;
  const int lrow = lane & 15, lk = lane >> 4;
  const int row0 = blockIdx.x * 64;
  const int m = blockIdx.y >> 1;
  const int half = blockIdx.y & 1;
  const short* low = m ? lowv : lowq;
  const short* B = m ? Bv2 : Bq2;
  float* op = out + (size_t)m * T_TOKENS * QOUT;

  s16x8 a[4][4];
#pragma unroll
  for (int rt = 0; rt < 4; ++rt)
#pragma unroll
    for (int kk = 0; kk < 4; ++kk)
      a[rt][kk] = *(const s16x8*)(low + (size_t)(row0 + rt * 16 + lrow) * 128 + kk * 32 + lk * 8);

#pragma unroll
  for (int sub = 0; sub < 4; ++sub) {
    int cb = half * 1024 + sub * 256 + wv * 64;
    f32x4 acc[4][4] = {};
#pragma unroll
    for (int kk = 0; kk < 4; ++kk) {
      s16x8 b[4];
#pragma unroll
      for (int ct = 0; ct < 4; ++ct) {
        int c = cb + ct * 16 + lrow;
        b[ct] = *(const s16x8*)(B + ((size_t)(kk * 4 + lk) * QOUT + c) * 8);
      }
#pragma unroll
      for (int rt = 0; rt < 4; ++rt)
#pragma unroll
        for (int ct = 0; ct < 4; ++ct)
          acc[rt][ct] = __builtin_amdgcn_mfma_f32_16x16x32_bf16(b[ct], a[rt][kk], acc[rt][ct], 0, 0, 0);
    }
#pragma unroll
    for (int rt = 0; rt < 4; ++rt)
#pragma unroll
      for (int ct = 0; ct < 4; ++ct) {
        int t = row0 + rt * 16 + lrow;
        int col = cb + ct * 16 + lk * 4;
        *(f32x4*)(op + (size_t)t * QOUT + col) = acc[rt][ct];
      }
  }
}

extern "C" void kernel_launch(void* const* d_in, const int* in_sizes, int n_in,
                              void* d_out, int out_size, void* d_ws, size_t ws_size,
                              hipStream_t stream) {
  const float* h  = (const float*)d_in[0];
  const float* rw = (const float*)d_in[1];
  const float* qa = (const float*)d_in[2];
  const float* qb = (const float*)d_in[3];
  const float* va = (const float*)d_in[4];
  const float* vb = (const float*)d_in[5];
  float* out = (float*)d_out;
  char* ws = (char*)d_ws;

  short* Bq1 = (short*)(ws);                    // 512 KB each
  short* Bv1 = (short*)(ws + (512 << 10));
  short* Bq2 = (short*)(ws + (1024 << 10));
  short* Bv2 = (short*)(ws + (1536 << 10));
  short* lowq = (short*)(ws + (2 << 20));       // 4 MB each
  short* lowv = (short*)(ws + (6 << 20));

  k_pack<<<512, 256, 0, stream>>>(qa, qb, va, vb, Bq1, Bv1, Bq2, Bv2);
  k_s1<<<T_TOKENS / 32, 256, 0, stream>>>(h, rw, Bq1, Bv1, lowq, lowv);
  dim3 g2(T_TOKENS / 64, 4);
  k_up<<<g2, 256, 0, stream>>>(lowq, lowv, Bq2, Bv2, out);
}

// Round 4
// 143.106 us; speedup vs baseline: 1.5531x; 1.0882x over previous
//
#include <hip/hip_runtime.h>

#define T_TOKENS 16384
#define DIM 2048
#define NE 8
#define QOUT 2048
#define LSCALE 2.0f

typedef __attribute__((ext_vector_type(4))) float f32x4;
typedef __attribute__((ext_vector_type(8))) short s16x8;
typedef __attribute__((ext_vector_type(4))) short s16x4;

__device__ __forceinline__ short f2bf(float f) {
  unsigned u = __builtin_bit_cast(unsigned, f);
  u += 0x7fffu + ((u >> 16) & 1u);   // round-to-nearest-even
  return (short)(u >> 16);
}

// LDS-only barrier: drains lgkm (ds_write visibility) but leaves global
// prefetch loads (vmcnt) in flight across the barrier.
__device__ __forceinline__ void barrier_lds() {
  asm volatile("s_waitcnt lgkmcnt(0)" ::: "memory");
  __builtin_amdgcn_s_barrier();
}

// ---------------------------------------------------------------------------
// Pack LoRA weights (f32) into bf16 MFMA-fragment layout.
// lora_a [E][D][R]  -> P1[d8][col=e*16+r][j]  (d = d8*8+j), col in [0,128)
// lora_b [E][R][QO] -> P2[k8][c][j]           (k = k8*8+j = e*16+r)
// ---------------------------------------------------------------------------
__global__ __launch_bounds__(256) void k_pack(
    const float* __restrict__ qa, const float* __restrict__ qb,
    const float* __restrict__ va, const float* __restrict__ vb,
    short* __restrict__ Bq1, short* __restrict__ Bv1,
    short* __restrict__ Bq2, short* __restrict__ Bv2) {
  int tid = blockIdx.x * 256 + threadIdx.x;  // 131072 threads
  if (tid < 65536) {
    int mat = tid >> 15;
    int idx = tid & 32767;          // d8*128 + col
    int d8 = idx >> 7, c = idx & 127;
    int e = c >> 4, r = c & 15;
    const float* src = mat ? va : qa;
    short* dst = mat ? Bv1 : Bq1;
    s16x8 v;
#pragma unroll
    for (int j = 0; j < 8; ++j)
      v[j] = f2bf(src[((size_t)e * DIM + d8 * 8 + j) * 16 + r]);
    *(s16x8*)(dst + (size_t)idx * 8) = v;
  } else {
    int t2 = tid - 65536;
    int mat = t2 >> 15;
    int idx = t2 & 32767;           // k8*2048 + c
    int k8 = idx >> 11, c = idx & 2047;
    const float* src = mat ? vb : qb;
    short* dst = mat ? Bv2 : Bq2;
    s16x8 v;
#pragma unroll
    for (int j = 0; j < 8; ++j)
      v[j] = f2bf(src[(size_t)(k8 * 8 + j) * QOUT + c]);
    *(s16x8*)(dst + (size_t)idx * 8) = v;
  }
}

// ---------------------------------------------------------------------------
// Fused stage 1: routing (f32-exact) + low = (h @ Acat) * w.
// Block = 64 tokens x 256 cols, 8 waves: wave wv -> token-half (wv>>2),
// cols (wv&3)*64.  Per K-step(32): thread (r=tid>>3, kq=(tid&7)*4) loads one
// distinct float4 of the 64x32 h tile; 1-deep prefetch of next hv + B-frags
// kept in flight across the LDS-only barrier.  Routing partials accumulate
// f32 from LDS-staged router weights (wave-broadcast reads).
// ---------------------------------------------------------------------------
__global__ __launch_bounds__(512, 4) void k_s1(
    const float* __restrict__ h, const float* __restrict__ rw,
    const short* __restrict__ Bq1, const short* __restrict__ Bv1,
    short* __restrict__ lowq, short* __restrict__ lowv) {
  __shared__ float rwl[NE * DIM];       // 64 KB
  __shared__ short At[2][64][40];       // 10 KB, padded rows (80 B)
  __shared__ float wl[64][NE];          // 2 KB

  const int tid = threadIdx.x;
  const int lane = tid & 63, wv = tid >> 6;
  const int lrow = lane & 15, lk = lane >> 4;
  const int row0 = blockIdx.x * 64;
  const int rh = wv >> 2;               // token half
  const int c0 = (wv & 3) * 64;         // col group
  const int r = tid >> 3;               // 0..63
  const int kq = (tid & 7) * 4;

  {  // stage router weights (16384 f32) into LDS
    const float4* src = (const float4*)rw;
    float4* dst = (float4*)rwl;
#pragma unroll
    for (int i = 0; i < 8; ++i) dst[tid + i * 512] = src[tid + i * 512];
  }
  __syncthreads();

  const float* hrow = h + (size_t)(row0 + r) * DIM;
  const short* bp[4]; int cc4[4];
#pragma unroll
  for (int ct = 0; ct < 4; ++ct) {
    int c = c0 + ct * 16 + lrow;
    bp[ct] = (c < 128) ? Bq1 : Bv1;
    cc4[ct] = c & 127;
  }

  // prologue loads (kb = 0)
  float4 hv = *(const float4*)(hrow + kq);
  s16x8 b[4];
#pragma unroll
  for (int ct = 0; ct < 4; ++ct)
    b[ct] = *(const s16x8*)(bp[ct] + ((size_t)lk * 128 + cc4[ct]) * 8);

  float lg[NE] = {0.f, 0.f, 0.f, 0.f, 0.f, 0.f, 0.f, 0.f};
  f32x4 acc[2][4] = {};
  int cur = 0;

  for (int kb = 0; kb < DIM; kb += 32) {
    const int kn = (kb + 32) & (DIM - 1);   // wraps to 0 on last iter (unused)
    float4 hvn = *(const float4*)(hrow + kn + kq);
    s16x8 bn[4];
#pragma unroll
    for (int ct = 0; ct < 4; ++ct)
      bn[ct] = *(const s16x8*)(bp[ct] + ((size_t)((kn >> 3) + lk) * 128 + cc4[ct]) * 8);
    // routing partials (wave-broadcast LDS reads, f32 VALU)
#pragma unroll
    for (int e = 0; e < NE; ++e) {
      float4 rv = *(const float4*)&rwl[e * DIM + kb + kq];
      lg[e] += hv.x * rv.x + hv.y * rv.y + hv.z * rv.z + hv.w * rv.w;
    }
    // convert + stage A tile
    s16x4 hb4;
    hb4[0] = f2bf(hv.x); hb4[1] = f2bf(hv.y);
    hb4[2] = f2bf(hv.z); hb4[3] = f2bf(hv.w);
    *(s16x4*)&At[cur][r][kq] = hb4;
    barrier_lds();                          // lgkm drain only; vmcnt stays
    s16x8 a[2];
#pragma unroll
    for (int rt = 0; rt < 2; ++rt)
      a[rt] = *(const s16x8*)&At[cur][rh * 32 + rt * 16 + lrow][lk * 8];
#pragma unroll
    for (int rt = 0; rt < 2; ++rt)
#pragma unroll
      for (int ct = 0; ct < 4; ++ct)
        acc[rt][ct] = __builtin_amdgcn_mfma_f32_16x16x32_bf16(b[ct], a[rt], acc[rt][ct], 0, 0, 0);
    hv = hvn;
#pragma unroll
    for (int ct = 0; ct < 4; ++ct) b[ct] = bn[ct];
    cur ^= 1;
  }

  // reduce logits across the 8 k-lanes of each row
#pragma unroll
  for (int e = 0; e < NE; ++e) {
    lg[e] += __shfl_xor(lg[e], 1, 64);
    lg[e] += __shfl_xor(lg[e], 2, 64);
    lg[e] += __shfl_xor(lg[e], 4, 64);
  }
  // softmax + top-2 (redundant across 8 lanes of a row; deterministic)
  float mx = lg[0];
#pragma unroll
  for (int e = 1; e < NE; ++e) mx = fmaxf(mx, lg[e]);
  float p[NE], sum = 0.f;
#pragma unroll
  for (int e = 0; e < NE; ++e) { p[e] = expf(lg[e] - mx); sum += p[e]; }
  int i1 = 0; float v1 = p[0];
#pragma unroll
  for (int e = 1; e < NE; ++e) if (p[e] > v1) { v1 = p[e]; i1 = e; }
  float v2 = -1.f; int i2 = 0;
#pragma unroll
  for (int e = 0; e < NE; ++e) if (e != i1 && p[e] > v2) { v2 = p[e]; i2 = e; }
  float s1 = v1 / sum, s2 = v2 / sum;
  float dn = s1 + s2 + 1e-20f;
  float w1 = s1 / dn * LSCALE, w2 = s2 / dn * LSCALE;
  int el = tid & 7;
  wl[r][el] = (el == i1) ? w1 : ((el == i2) ? w2 : 0.f);
  __syncthreads();

  // scale + store low (operand-swapped layout: token=lane&15, cols=lk*4+j)
#pragma unroll
  for (int rt = 0; rt < 2; ++rt)
#pragma unroll
    for (int ct = 0; ct < 4; ++ct) {
      int rr = rh * 32 + rt * 16 + lrow;
      int t = row0 + rr;
      int col = c0 + ct * 16 + lk * 4;
      int cc = col & 127;
      int e = cc >> 4;
      short* op = (col < 128) ? lowq : lowv;
      float wgt = wl[rr][e];
      s16x4 v;
#pragma unroll
      for (int j = 0; j < 4; ++j) v[j] = f2bf(acc[rt][ct][j] * wgt);
      *(s16x4*)(op + (size_t)t * 128 + cc) = v;
    }
}

// ---------------------------------------------------------------------------
// Stage 2: delta = low[T,128] @ B[128,2048].  Block = 64 tokens x 1024 cols.
// A-frags (full K=128) preloaded in registers; 4 serial 256-col subtiles.
// launch_bounds(256,3) -> 3 blocks/CU for store/load overlap.
// ---------------------------------------------------------------------------
__global__ __launch_bounds__(256, 3) void k_up(
    const short* __restrict__ lowq, const short* __restrict__ lowv,
    const short* __restrict__ Bq2, const short* __restrict__ Bv2,
    float* __restrict__ out) {
  const int lane = threadIdx.x & 63, wv = threadIdx.x >> 6;
  const int lrow = lane & 15, lk = lane >> 4;
  const int row0 = blockIdx.x * 64;
  const int m = blockIdx.y >> 1;
  const int half = blockIdx.y & 1;
  const short* low = m ? lowv : lowq;
  const short* B = m ? Bv2 : Bq2;
  float* op = out + (size_t)m * T_TOKENS * QOUT;

  s16x8 a[4][4];
#pragma unroll
  for (int rt = 0; rt < 4; ++rt)
#pragma unroll
    for (int kk = 0; kk < 4; ++kk)
      a[rt][kk] = *(const s16x8*)(low + (size_t)(row0 + rt * 16 + lrow) * 128 + kk * 32 + lk * 8);

#pragma unroll
  for (int sub = 0; sub < 4; ++sub) {
    int cb = half * 1024 + sub * 256 + wv * 64;
    f32x4 acc[4][4] = {};
#pragma unroll
    for (int kk = 0; kk < 4; ++kk) {
      s16x8 b[4];
#pragma unroll
      for (int ct = 0; ct < 4; ++ct) {
        int c = cb + ct * 16 + lrow;
        b[ct] = *(const s16x8*)(B + ((size_t)(kk * 4 + lk) * QOUT + c) * 8);
      }
#pragma unroll
      for (int rt = 0; rt < 4; ++rt)
#pragma unroll
        for (int ct = 0; ct < 4; ++ct)
          acc[rt][ct] = __builtin_amdgcn_mfma_f32_16x16x32_bf16(b[ct], a[rt][kk], acc[rt][ct], 0, 0, 0);
    }
#pragma unroll
    for (int rt = 0; rt < 4; ++rt)
#pragma unroll
      for (int ct = 0; ct < 4; ++ct) {
        int t = row0 + rt * 16 + lrow;
        int col = cb + ct * 16 + lk * 4;
        *(f32x4*)(op + (size_t)t * QOUT + col) = acc[rt][ct];
      }
  }
}

extern "C" void kernel_launch(void* const* d_in, const int* in_sizes, int n_in,
                              void* d_out, int out_size, void* d_ws, size_t ws_size,
                              hipStream_t stream) {
  const float* h  = (const float*)d_in[0];
  const float* rw = (const float*)d_in[1];
  const float* qa = (const float*)d_in[2];
  const float* qb = (const float*)d_in[3];
  const float* va = (const float*)d_in[4];
  const float* vb = (const float*)d_in[5];
  float* out = (float*)d_out;
  char* ws = (char*)d_ws;

  short* Bq1 = (short*)(ws);                    // 512 KB each
  short* Bv1 = (short*)(ws + (512 << 10));
  short* Bq2 = (short*)(ws + (1024 << 10));
  short* Bv2 = (short*)(ws + (1536 << 10));
  short* lowq = (short*)(ws + (2 << 20));       // 4 MB each
  short* lowv = (short*)(ws + (6 << 20));

  k_pack<<<512, 256, 0, stream>>>(qa, qb, va, vb, Bq1, Bv1, Bq2, Bv2);
  k_s1<<<T_TOKENS / 64, 512, 0, stream>>>(h, rw, Bq1, Bv1, lowq, lowv);
  dim3 g2(T_TOKENS / 64, 4);
  k_up<<<g2, 256, 0, stream>>>(lowq, lowv, Bq2, Bv2, out);
}